// Round 1
// baseline (854.827 us; speedup 1.0000x reference)
//
#include <hip/hip_runtime.h>

typedef __attribute__((ext_vector_type(8))) short short8;
typedef __attribute__((ext_vector_type(4))) float f32x4;

#define AS3P(x) ((__attribute__((address_space(3))) void*)(x))
#define AS1P(x) ((const __attribute__((address_space(1))) void*)(x))

__device__ __forceinline__ unsigned short f2bf(float f) {
    unsigned int u = __float_as_uint(f);
    u += 0x7fffu + ((u >> 16) & 1u);   // RNE
    return (unsigned short)(u >> 16);
}
__device__ __forceinline__ float bf2f(unsigned short b) {
    return __uint_as_float(((unsigned int)b) << 16);
}
__device__ __forceinline__ float waveReduceSum(float v) {
    #pragma unroll
    for (int off = 32; off; off >>= 1) v += __shfl_xor(v, off, 64);
    return v;
}

// ---------------- small prep kernels ----------------

__global__ void k_norm_protos(const float* __restrict__ proto, float* __restrict__ protos_n) {
    int w = threadIdx.x >> 6, l = threadIdx.x & 63;
    float v = proto[w * 64 + l];
    float ss = waveReduceSum(v * v);
    float inv = 1.f / fmaxf(sqrtf(ss), 1e-12f);
    protos_n[w * 64 + l] = v * inv;
}

__global__ __launch_bounds__(256) void k_prep_items(const float* __restrict__ item_emb,
                                                    const float* __restrict__ protos_n,
                                                    float* __restrict__ items_n,
                                                    float* __restrict__ cates,
                                                    float* __restrict__ catesT) {
    __shared__ float sp[256];
    int tid = threadIdx.x;
    sp[tid] = protos_n[tid];
    __syncthreads();
    int i = blockIdx.x * 256 + tid;
    const float4* row = (const float4*)(item_emb + (size_t)i * 64);
    float4 f[16];
    float ss = 0.f;
    #pragma unroll
    for (int q = 0; q < 16; ++q) {
        f[q] = row[q];
        ss += f[q].x * f[q].x + f[q].y * f[q].y + f[q].z * f[q].z + f[q].w * f[q].w;
    }
    float inv = 1.f / fmaxf(sqrtf(ss), 1e-12f);
    float dots[4] = {0.f, 0.f, 0.f, 0.f};
    float4* on = (float4*)(items_n + (size_t)i * 64);
    #pragma unroll
    for (int q = 0; q < 16; ++q) {
        f[q].x *= inv; f[q].y *= inv; f[q].z *= inv; f[q].w *= inv;
        on[q] = f[q];
        #pragma unroll
        for (int k = 0; k < 4; ++k) {
            dots[k] += f[q].x * sp[k * 64 + q * 4 + 0] + f[q].y * sp[k * 64 + q * 4 + 1]
                     + f[q].z * sp[k * 64 + q * 4 + 2] + f[q].w * sp[k * 64 + q * 4 + 3];
        }
    }
    float m = fmaxf(fmaxf(dots[0], dots[1]), fmaxf(dots[2], dots[3]));
    float e0 = expf(dots[0] - m), e1 = expf(dots[1] - m), e2 = expf(dots[2] - m), e3 = expf(dots[3] - m);
    float is = 1.f / (e0 + e1 + e2 + e3);
    float4 c; c.x = e0 * is; c.y = e1 * is; c.z = e2 * is; c.w = e3 * is;
    *(float4*)(cates + (size_t)i * 4) = c;
    catesT[0 * 8192 + i] = c.x;
    catesT[1 * 8192 + i] = c.y;
    catesT[2 * 8192 + i] = c.z;
    catesT[3 * 8192 + i] = c.w;
}

// adjT[m][n] = (bf16)adj[n][m]
__global__ __launch_bounds__(256) void k_transpose_adj(const float* __restrict__ adj,
                                                       unsigned short* __restrict__ adjT) {
    __shared__ float t[64][65];
    int tid = threadIdx.x;
    int n0 = blockIdx.y * 64, m0 = blockIdx.x * 64;
    int rr = tid >> 4;
    int cc = (tid & 15) * 4;
    #pragma unroll
    for (int j = 0; j < 4; ++j) {
        int i = j * 16 + rr;
        float4 v = *(const float4*)(adj + (size_t)(n0 + i) * 8192 + m0 + cc);
        t[i][cc + 0] = v.x; t[i][cc + 1] = v.y; t[i][cc + 2] = v.z; t[i][cc + 3] = v.w;
    }
    __syncthreads();
    #pragma unroll
    for (int j = 0; j < 4; ++j) {
        int i = j * 16 + rr;
        ushort4 pk;
        pk.x = f2bf(t[cc + 0][i]);
        pk.y = f2bf(t[cc + 1][i]);
        pk.z = f2bf(t[cc + 2][i]);
        pk.w = f2bf(t[cc + 3][i]);
        *(ushort4*)(adjT + (size_t)(m0 + i) * 8192 + n0 + cc) = pk;
    }
}

// x_k rows: r = k*512 + b ; row-normalized rating*cate, stored bf16
__global__ __launch_bounds__(256) void k_xk(const float* __restrict__ rating,
                                            const float* __restrict__ catesT,
                                            unsigned short* __restrict__ xk) {
    int r = blockIdx.x;
    int k = r >> 9, b = r & 511;
    int tid = threadIdx.x;
    const float4* rat = (const float4*)(rating + (size_t)b * 8192);
    const float4* ct  = (const float4*)(catesT + (size_t)k * 8192);
    float4 v[8];
    float ss = 0.f;
    #pragma unroll
    for (int j = 0; j < 8; ++j) {
        int idx = tid + j * 256;
        float4 a = rat[idx], c = ct[idx];
        float4 p; p.x = a.x * c.x; p.y = a.y * c.y; p.z = a.z * c.z; p.w = a.w * c.w;
        v[j] = p;
        ss += p.x * p.x + p.y * p.y + p.z * p.z + p.w * p.w;
    }
    ss = waveReduceSum(ss);
    __shared__ float sred[4];
    if ((tid & 63) == 0) sred[tid >> 6] = ss;
    __syncthreads();
    float inv = 1.f / fmaxf(sqrtf(sred[0] + sred[1] + sred[2] + sred[3]), 1e-12f);
    #pragma unroll
    for (int j = 0; j < 8; ++j) {
        int idx = tid + j * 256;
        ushort4 pk;
        pk.x = f2bf(v[j].x * inv); pk.y = f2bf(v[j].y * inv);
        pk.z = f2bf(v[j].z * inv); pk.w = f2bf(v[j].w * inv);
        *(ushort4*)(xk + (size_t)r * 8192 + idx * 4) = pk;
    }
}

__global__ void k_f32_to_bf16(const float* __restrict__ in, unsigned short* __restrict__ out) {
    int i = blockIdx.x * 256 + threadIdx.x;
    float4 v = *(const float4*)(in + (size_t)i * 4);
    ushort4 pk; pk.x = f2bf(v.x); pk.y = f2bf(v.y); pk.z = f2bf(v.z); pk.w = f2bf(v.w);
    *(ushort4*)(out + (size_t)i * 4) = pk;
}

// ---------------- MFMA GEMM: C[M x Ncols] = A[M x K] * B^T, A/B bf16 row-major K-contig ----------------
// EPI 0: store bf16 ; EPI 1: store bf16 (acc + xk)/2 ; EPI 2: store f32 partial (split-K)
template <int EPI>
__global__ __launch_bounds__(256) void k_gemm(const unsigned short* __restrict__ A,
                                              const unsigned short* __restrict__ B,
                                              void* __restrict__ Cout,
                                              const unsigned short* __restrict__ xk,
                                              int M, int ksplit, int lda, int ldb, int ldc) {
    __shared__ unsigned short lA[128 * 64];
    __shared__ unsigned short lB[128 * 64];
    int tid = threadIdx.x;
    int lane = tid & 63;
    int w = tid >> 6;
    int wr = w >> 1, wc = w & 1;
    int mBase = blockIdx.y * 128;
    int nBase = blockIdx.x * 128;
    int Kbeg = blockIdx.z * ksplit;
    int Kend = Kbeg + ksplit;

    f32x4 acc[4][4] = {};

    const unsigned short* Ablk = A + (size_t)mBase * lda;
    const unsigned short* Bblk = B + (size_t)nBase * ldb;
    int srow = tid >> 3;                       // 0..31
    int scg = (tid & 7) ^ (srow & 7);          // pre-swizzled source col-group
    char* ldsA_w = (char*)lA + w * 1024;
    char* ldsB_w = (char*)lB + w * 1024;

    for (int k0 = Kbeg; k0 < Kend; k0 += 64) {
        __syncthreads();
        #pragma unroll
        for (int it = 0; it < 4; ++it) {
            const unsigned short* ga = Ablk + (size_t)(it * 32 + srow) * lda + k0 + scg * 8;
            __builtin_amdgcn_global_load_lds(AS1P(ga), AS3P(ldsA_w + it * 4096), 16, 0, 0);
            const unsigned short* gb = Bblk + (size_t)(it * 32 + srow) * ldb + k0 + scg * 8;
            __builtin_amdgcn_global_load_lds(AS1P(gb), AS3P(ldsB_w + it * 4096), 16, 0, 0);
        }
        __syncthreads();
        #pragma unroll
        for (int kk = 0; kk < 2; ++kk) {
            short8 af[4], bfr[4];
            #pragma unroll
            for (int i = 0; i < 4; ++i) {
                int rowa = wr * 64 + i * 16 + (lane & 15);
                int slot = kk * 4 + (lane >> 4);
                af[i] = *(const short8*)((const char*)lA + rowa * 128 + ((slot ^ (rowa & 7)) * 16));
                int rowb = wc * 64 + i * 16 + (lane & 15);
                bfr[i] = *(const short8*)((const char*)lB + rowb * 128 + ((slot ^ (rowb & 7)) * 16));
            }
            #pragma unroll
            for (int i = 0; i < 4; ++i)
                #pragma unroll
                for (int j = 0; j < 4; ++j)
                    acc[i][j] = __builtin_amdgcn_mfma_f32_16x16x32_bf16(af[i], bfr[j], acc[i][j], 0, 0, 0);
        }
    }

    #pragma unroll
    for (int i = 0; i < 4; ++i) {
        int rbase = mBase + wr * 64 + i * 16 + (lane >> 4) * 4;
        #pragma unroll
        for (int j = 0; j < 4; ++j) {
            int col = nBase + wc * 64 + j * 16 + (lane & 15);
            #pragma unroll
            for (int r = 0; r < 4; ++r) {
                size_t idx = (size_t)(rbase + r) * ldc + col;
                float v = acc[i][j][r];
                if (EPI == 0) {
                    ((unsigned short*)Cout)[idx] = f2bf(v);
                } else if (EPI == 1) {
                    float xv = bf2f(xk[idx]);
                    ((unsigned short*)Cout)[idx] = f2bf(0.5f * (v + xv));
                } else {
                    float* outP = (float*)Cout + (size_t)blockIdx.z * M * ldc;
                    outP[idx] = v;
                }
            }
        }
    }
}

// sum split-K partials + bias; write mu (normalized) and logvar to d_out
__global__ __launch_bounds__(128) void k_reduce_h(const float* __restrict__ hpart,
                                                  const float* __restrict__ enc_b,
                                                  float* __restrict__ outp) {
    int r = blockIdx.x;
    int o = threadIdx.x;
    float s = enc_b[o];
    #pragma unroll
    for (int sp = 0; sp < 8; ++sp) s += hpart[((size_t)sp * 2048 + r) * 128 + o];
    const size_t MU0 = (size_t)512 * 8192;
    const size_t LV0 = MU0 + (size_t)2048 * 64;
    if (o < 64) {
        float ss = s * s;
        #pragma unroll
        for (int off = 32; off; off >>= 1) ss += __shfl_xor(ss, off, 64);
        float inv = 1.f / fmaxf(sqrtf(ss), 1e-12f);
        outp[MU0 + (size_t)r * 64 + o] = s * inv;
    } else {
        outp[LV0 + (size_t)r * 64 + (o - 64)] = -s;
    }
}

__global__ __launch_bounds__(256) void k_logits(const float* __restrict__ items_n,
                                                const float* __restrict__ cates,
                                                const float* __restrict__ mu,
                                                float* __restrict__ out) {
    __shared__ float smu[256];
    int tid = threadIdx.x;
    int b = blockIdx.y;
    smu[tid] = mu[((size_t)(tid >> 6) * 512 + b) * 64 + (tid & 63)];
    __syncthreads();
    int n = blockIdx.x * 256 + tid;
    const float4* iv = (const float4*)(items_n + (size_t)n * 64);
    float d0 = 0.f, d1 = 0.f, d2 = 0.f, d3 = 0.f;
    #pragma unroll
    for (int q = 0; q < 16; ++q) {
        float4 x = iv[q];
        d0 += x.x * smu[0 + q * 4] + x.y * smu[0 + q * 4 + 1] + x.z * smu[0 + q * 4 + 2] + x.w * smu[0 + q * 4 + 3];
        d1 += x.x * smu[64 + q * 4] + x.y * smu[64 + q * 4 + 1] + x.z * smu[64 + q * 4 + 2] + x.w * smu[64 + q * 4 + 3];
        d2 += x.x * smu[128 + q * 4] + x.y * smu[128 + q * 4 + 1] + x.z * smu[128 + q * 4 + 2] + x.w * smu[128 + q * 4 + 3];
        d3 += x.x * smu[192 + q * 4] + x.y * smu[192 + q * 4 + 1] + x.z * smu[192 + q * 4 + 2] + x.w * smu[192 + q * 4 + 3];
    }
    float4 c = *(const float4*)(cates + (size_t)n * 4);
    float p = expf(d0) * c.x + expf(d1) * c.y + expf(d2) * c.z + expf(d3) * c.w;
    out[(size_t)b * 8192 + n] = logf(p);
}

extern "C" void kernel_launch(void* const* d_in, const int* in_sizes, int n_in,
                              void* d_out, int out_size, void* d_ws, size_t ws_size,
                              hipStream_t stream) {
    const float* rating   = (const float*)d_in[0];   // [512][8192]
    const float* adj      = (const float*)d_in[1];   // [8192][8192]
    const float* item_emb = (const float*)d_in[2];   // [8192][64]
    const float* proto    = (const float*)d_in[3];   // [4][64]
    const float* enc_w    = (const float*)d_in[4];   // [128][8192]
    const float* enc_b    = (const float*)d_in[5];   // [128]
    float* out = (float*)d_out;

    char* ws = (char*)d_ws;
    unsigned short* adjT = (unsigned short*)ws;                       // 8192*8192 bf16 = 128MB
    unsigned short* xk   = (unsigned short*)(ws + (size_t)134217728); // 2048*8192
    unsigned short* tmp1 = xk + (size_t)2048 * 8192;
    unsigned short* xbuf = tmp1 + (size_t)2048 * 8192;
    float* protos_n = (float*)(xbuf + (size_t)2048 * 8192);           // 256
    float* items_n  = protos_n + 256;                                 // 8192*64
    float* cates    = items_n + (size_t)8192 * 64;                    // 8192*4
    float* catesT   = cates + (size_t)8192 * 4;                       // 4*8192
    unsigned short* encw = (unsigned short*)(catesT + (size_t)8192 * 4); // 128*8192 bf16
    float* hpart = (float*)(encw + (size_t)128 * 8192);               // 8*2048*128 f32

    k_norm_protos<<<1, 256, 0, stream>>>(proto, protos_n);
    k_prep_items<<<32, 256, 0, stream>>>(item_emb, protos_n, items_n, cates, catesT);
    k_transpose_adj<<<dim3(128, 128), 256, 0, stream>>>(adj, adjT);
    k_xk<<<2048, 256, 0, stream>>>(rating, catesT, xk);

    // tmp1 = x_k @ adj   (B^T = adjT)
    k_gemm<0><<<dim3(64, 16, 1), 256, 0, stream>>>(xk, adjT, tmp1, nullptr, 2048, 8192, 8192, 8192, 8192);
    // xbuf = (tmp1 @ adj + x_k)/2
    k_gemm<1><<<dim3(64, 16, 1), 256, 0, stream>>>(tmp1, adjT, xbuf, xk, 2048, 8192, 8192, 8192, 8192);

    k_f32_to_bf16<<<1024, 256, 0, stream>>>(enc_w, encw);
    // h partials: split-K = 8, each 1024
    k_gemm<2><<<dim3(1, 16, 8), 256, 0, stream>>>(xbuf, encw, hpart, nullptr, 2048, 1024, 8192, 8192, 128);
    k_reduce_h<<<2048, 128, 0, stream>>>(hpart, enc_b, out);

    k_logits<<<dim3(32, 512), 256, 0, stream>>>(items_n, cates, out + (size_t)512 * 8192, out);
}

// Round 2
// 265.557 us; speedup vs baseline: 3.2190x; 3.2190x over previous
//
#include <hip/hip_runtime.h>

typedef __attribute__((ext_vector_type(8))) short short8;
typedef __attribute__((ext_vector_type(4))) float f32x4;

#define AS3P(x) ((__attribute__((address_space(3))) void*)(x))
#define AS1P(x) ((const __attribute__((address_space(1))) void*)(x))

__device__ __forceinline__ unsigned short f2bf(float f) {
    unsigned int u = __float_as_uint(f);
    u += 0x7fffu + ((u >> 16) & 1u);   // RNE
    return (unsigned short)(u >> 16);
}
__device__ __forceinline__ float waveReduceSum(float v) {
    #pragma unroll
    for (int off = 32; off; off >>= 1) v += __shfl_xor(v, off, 64);
    return v;
}

// ---------------- small prep kernels ----------------

__global__ void k_norm_protos(const float* __restrict__ proto, float* __restrict__ protos_n) {
    int w = threadIdx.x >> 6, l = threadIdx.x & 63;
    float v = proto[w * 64 + l];
    float ss = waveReduceSum(v * v);
    float inv = 1.f / fmaxf(sqrtf(ss), 1e-12f);
    protos_n[w * 64 + l] = v * inv;
}

__global__ __launch_bounds__(256) void k_prep_items(const float* __restrict__ item_emb,
                                                    const float* __restrict__ protos_n,
                                                    float* __restrict__ items_n,
                                                    float* __restrict__ cates,
                                                    float* __restrict__ catesT) {
    __shared__ float sp[256];
    int tid = threadIdx.x;
    sp[tid] = protos_n[tid];
    __syncthreads();
    int i = blockIdx.x * 256 + tid;
    const float4* row = (const float4*)(item_emb + (size_t)i * 64);
    float4 f[16];
    float ss = 0.f;
    #pragma unroll
    for (int q = 0; q < 16; ++q) {
        f[q] = row[q];
        ss += f[q].x * f[q].x + f[q].y * f[q].y + f[q].z * f[q].z + f[q].w * f[q].w;
    }
    float inv = 1.f / fmaxf(sqrtf(ss), 1e-12f);
    float dots[4] = {0.f, 0.f, 0.f, 0.f};
    float4* on = (float4*)(items_n + (size_t)i * 64);
    #pragma unroll
    for (int q = 0; q < 16; ++q) {
        f[q].x *= inv; f[q].y *= inv; f[q].z *= inv; f[q].w *= inv;
        on[q] = f[q];
        #pragma unroll
        for (int k = 0; k < 4; ++k) {
            dots[k] += f[q].x * sp[k * 64 + q * 4 + 0] + f[q].y * sp[k * 64 + q * 4 + 1]
                     + f[q].z * sp[k * 64 + q * 4 + 2] + f[q].w * sp[k * 64 + q * 4 + 3];
        }
    }
    float m = fmaxf(fmaxf(dots[0], dots[1]), fmaxf(dots[2], dots[3]));
    float e0 = expf(dots[0] - m), e1 = expf(dots[1] - m), e2 = expf(dots[2] - m), e3 = expf(dots[3] - m);
    float is = 1.f / (e0 + e1 + e2 + e3);
    float4 c; c.x = e0 * is; c.y = e1 * is; c.z = e2 * is; c.w = e3 * is;
    *(float4*)(cates + (size_t)i * 4) = c;
    catesT[0 * 8192 + i] = c.x;
    catesT[1 * 8192 + i] = c.y;
    catesT[2 * 8192 + i] = c.z;
    catesT[3 * 8192 + i] = c.w;
}

// streaming f32 -> bf16 (8 elements/thread)
__global__ __launch_bounds__(256) void k_cast_bf16_x8(const float* __restrict__ in,
                                                      unsigned short* __restrict__ out) {
    size_t i = ((size_t)blockIdx.x * 256 + threadIdx.x) * 8;
    float4 a = *(const float4*)(in + i);
    float4 b = *(const float4*)(in + i + 4);
    uint4 pk;
    pk.x = (unsigned int)f2bf(a.x) | ((unsigned int)f2bf(a.y) << 16);
    pk.y = (unsigned int)f2bf(a.z) | ((unsigned int)f2bf(a.w) << 16);
    pk.z = (unsigned int)f2bf(b.x) | ((unsigned int)f2bf(b.y) << 16);
    pk.w = (unsigned int)f2bf(b.z) | ((unsigned int)f2bf(b.w) << 16);
    *(uint4*)(out + i) = pk;
}

// x_k rows: r = k*512 + b ; row-normalized rating*cate, stored bf16
__global__ __launch_bounds__(256) void k_xk(const float* __restrict__ rating,
                                            const float* __restrict__ catesT,
                                            unsigned short* __restrict__ xk) {
    int r = blockIdx.x;
    int k = r >> 9, b = r & 511;
    int tid = threadIdx.x;
    const float4* rat = (const float4*)(rating + (size_t)b * 8192);
    const float4* ct  = (const float4*)(catesT + (size_t)k * 8192);
    float4 v[8];
    float ss = 0.f;
    #pragma unroll
    for (int j = 0; j < 8; ++j) {
        int idx = tid + j * 256;
        float4 a = rat[idx], c = ct[idx];
        float4 p; p.x = a.x * c.x; p.y = a.y * c.y; p.z = a.z * c.z; p.w = a.w * c.w;
        v[j] = p;
        ss += p.x * p.x + p.y * p.y + p.z * p.z + p.w * p.w;
    }
    ss = waveReduceSum(ss);
    __shared__ float sred[4];
    if ((tid & 63) == 0) sred[tid >> 6] = ss;
    __syncthreads();
    float inv = 1.f / fmaxf(sqrtf(sred[0] + sred[1] + sred[2] + sred[3]), 1e-12f);
    #pragma unroll
    for (int j = 0; j < 8; ++j) {
        int idx = tid + j * 256;
        ushort4 pk;
        pk.x = f2bf(v[j].x * inv); pk.y = f2bf(v[j].y * inv);
        pk.z = f2bf(v[j].z * inv); pk.w = f2bf(v[j].w * inv);
        *(ushort4*)(xk + (size_t)r * 8192 + idx * 4) = pk;
    }
}

// ---------------- MFMA GEMM: partials[z][M][ldc] = A[M x Kslice] * B^T ----------------
// A,B bf16 row-major K-contiguous. Writes f32 split-K partials.
__global__ __launch_bounds__(256) void k_gemm_part(const unsigned short* __restrict__ A,
                                                   const unsigned short* __restrict__ B,
                                                   float* __restrict__ Cout,
                                                   int M, int ksplit, int lda, int ldb, int ldc) {
    __shared__ unsigned short lA[128 * 64];
    __shared__ unsigned short lB[128 * 64];
    int tid = threadIdx.x;
    int lane = tid & 63;
    int w = tid >> 6;
    int wr = w >> 1, wc = w & 1;
    int mBase = blockIdx.y * 128;
    int nBase = blockIdx.x * 128;
    int Kbeg = blockIdx.z * ksplit;
    int Kend = Kbeg + ksplit;

    f32x4 acc[4][4] = {};

    const unsigned short* Ablk = A + (size_t)mBase * lda;
    const unsigned short* Bblk = B + (size_t)nBase * ldb;
    int srow = tid >> 3;                       // 0..31
    int scg = (tid & 7) ^ (srow & 7);          // pre-swizzled source col-group
    char* ldsA_w = (char*)lA + w * 1024;
    char* ldsB_w = (char*)lB + w * 1024;

    for (int k0 = Kbeg; k0 < Kend; k0 += 64) {
        __syncthreads();
        #pragma unroll
        for (int it = 0; it < 4; ++it) {
            const unsigned short* ga = Ablk + (size_t)(it * 32 + srow) * lda + k0 + scg * 8;
            __builtin_amdgcn_global_load_lds(AS1P(ga), AS3P(ldsA_w + it * 4096), 16, 0, 0);
            const unsigned short* gb = Bblk + (size_t)(it * 32 + srow) * ldb + k0 + scg * 8;
            __builtin_amdgcn_global_load_lds(AS1P(gb), AS3P(ldsB_w + it * 4096), 16, 0, 0);
        }
        __syncthreads();
        #pragma unroll
        for (int kk = 0; kk < 2; ++kk) {
            short8 af[4], bfr[4];
            #pragma unroll
            for (int i = 0; i < 4; ++i) {
                int rowa = wr * 64 + i * 16 + (lane & 15);
                int slot = kk * 4 + (lane >> 4);
                af[i] = *(const short8*)((const char*)lA + rowa * 128 + ((slot ^ (rowa & 7)) * 16));
                int rowb = wc * 64 + i * 16 + (lane & 15);
                bfr[i] = *(const short8*)((const char*)lB + rowb * 128 + ((slot ^ (rowb & 7)) * 16));
            }
            #pragma unroll
            for (int i = 0; i < 4; ++i)
                #pragma unroll
                for (int j = 0; j < 4; ++j)
                    acc[i][j] = __builtin_amdgcn_mfma_f32_16x16x32_bf16(af[i], bfr[j], acc[i][j], 0, 0, 0);
        }
    }

    float* outP = Cout + (size_t)blockIdx.z * M * ldc;
    #pragma unroll
    for (int i = 0; i < 4; ++i) {
        int rbase = mBase + wr * 64 + i * 16 + (lane >> 4) * 4;
        #pragma unroll
        for (int j = 0; j < 4; ++j) {
            int col = nBase + wc * 64 + j * 16 + (lane & 15);
            #pragma unroll
            for (int r = 0; r < 4; ++r) {
                outP[(size_t)(rbase + r) * ldc + col] = acc[i][j][r];
            }
        }
    }
}

// sum SPLITK partials [sp][8192][128] over sp for a 64-row tile, transpose,
// optionally fold +enc_w and *0.5, store bf16 transposed: outT[o][m] (o<128, m<8192)
template <int SPLITK, bool ADDW>
__global__ __launch_bounds__(256) void k_reduce_T(const float* __restrict__ part,
                                                  const float* __restrict__ enc_w,
                                                  unsigned short* __restrict__ outT) {
    __shared__ float t[64 * 129];
    int m0 = blockIdx.x * 64;
    int tid = threadIdx.x;
    #pragma unroll
    for (int j = 0; j < 8; ++j) {
        int f = tid + j * 256;                 // float4 index within 64x128 tile
        float4 a = {0.f, 0.f, 0.f, 0.f};
        #pragma unroll
        for (int sp = 0; sp < SPLITK; ++sp) {
            const float4* p = (const float4*)(part + ((size_t)sp * 8192 + m0) * 128);
            float4 v = p[f];
            a.x += v.x; a.y += v.y; a.z += v.z; a.w += v.w;
        }
        int m = f >> 5, o = (f & 31) * 4;
        t[m * 129 + o + 0] = a.x; t[m * 129 + o + 1] = a.y;
        t[m * 129 + o + 2] = a.z; t[m * 129 + o + 3] = a.w;
    }
    __syncthreads();
    #pragma unroll
    for (int j = 0; j < 16; ++j) {
        int idx = tid + j * 256;
        int o = idx >> 5, mp = idx & 31;
        float v0 = t[(mp * 2 + 0) * 129 + o];
        float v1 = t[(mp * 2 + 1) * 129 + o];
        if (ADDW) {
            v0 = 0.5f * (v0 + enc_w[(size_t)o * 8192 + m0 + mp * 2 + 0]);
            v1 = 0.5f * (v1 + enc_w[(size_t)o * 8192 + m0 + mp * 2 + 1]);
        }
        unsigned int pk = (unsigned int)f2bf(v0) | ((unsigned int)f2bf(v1) << 16);
        *(unsigned int*)(outT + (size_t)o * 8192 + m0 + mp * 2) = pk;
    }
}

// sum split-K partials + bias; write mu (normalized) and logvar to d_out
__global__ __launch_bounds__(128) void k_reduce_h(const float* __restrict__ hpart,
                                                  const float* __restrict__ enc_b,
                                                  float* __restrict__ outp) {
    int r = blockIdx.x;
    int o = threadIdx.x;
    float s = enc_b[o];
    #pragma unroll
    for (int sp = 0; sp < 8; ++sp) s += hpart[((size_t)sp * 2048 + r) * 128 + o];
    const size_t MU0 = (size_t)512 * 8192;
    const size_t LV0 = MU0 + (size_t)2048 * 64;
    if (o < 64) {
        float ss = s * s;
        #pragma unroll
        for (int off = 32; off; off >>= 1) ss += __shfl_xor(ss, off, 64);
        float inv = 1.f / fmaxf(sqrtf(ss), 1e-12f);
        outp[MU0 + (size_t)r * 64 + o] = s * inv;
    } else {
        outp[LV0 + (size_t)r * 64 + (o - 64)] = -s;
    }
}

// logits: 4 batches per block to reuse the items registers
__global__ __launch_bounds__(256) void k_logits(const float* __restrict__ items_n,
                                                const float* __restrict__ cates,
                                                const float* __restrict__ mu,
                                                float* __restrict__ out) {
    __shared__ float smu[4 * 256];
    int tid = threadIdx.x;
    int b0 = blockIdx.y * 4;
    int k = tid >> 6, d = tid & 63;
    #pragma unroll
    for (int j = 0; j < 4; ++j)
        smu[j * 256 + tid] = mu[((size_t)k * 512 + b0 + j) * 64 + d];
    __syncthreads();
    int n = blockIdx.x * 256 + tid;
    float4 iv[16];
    const float4* ivp = (const float4*)(items_n + (size_t)n * 64);
    #pragma unroll
    for (int q = 0; q < 16; ++q) iv[q] = ivp[q];
    float4 c = *(const float4*)(cates + (size_t)n * 4);
    #pragma unroll
    for (int j = 0; j < 4; ++j) {
        const float* sm = smu + j * 256;
        float d0 = 0.f, d1 = 0.f, d2 = 0.f, d3 = 0.f;
        #pragma unroll
        for (int q = 0; q < 16; ++q) {
            float4 x = iv[q];
            d0 += x.x * sm[0 + q * 4] + x.y * sm[0 + q * 4 + 1] + x.z * sm[0 + q * 4 + 2] + x.w * sm[0 + q * 4 + 3];
            d1 += x.x * sm[64 + q * 4] + x.y * sm[64 + q * 4 + 1] + x.z * sm[64 + q * 4 + 2] + x.w * sm[64 + q * 4 + 3];
            d2 += x.x * sm[128 + q * 4] + x.y * sm[128 + q * 4 + 1] + x.z * sm[128 + q * 4 + 2] + x.w * sm[128 + q * 4 + 3];
            d3 += x.x * sm[192 + q * 4] + x.y * sm[192 + q * 4 + 1] + x.z * sm[192 + q * 4 + 2] + x.w * sm[192 + q * 4 + 3];
        }
        float p = expf(d0) * c.x + expf(d1) * c.y + expf(d2) * c.z + expf(d3) * c.w;
        out[(size_t)(b0 + j) * 8192 + n] = logf(p);
    }
}

extern "C" void kernel_launch(void* const* d_in, const int* in_sizes, int n_in,
                              void* d_out, int out_size, void* d_ws, size_t ws_size,
                              hipStream_t stream) {
    const float* rating   = (const float*)d_in[0];   // [512][8192]
    const float* adj      = (const float*)d_in[1];   // [8192][8192]
    const float* item_emb = (const float*)d_in[2];   // [8192][64]
    const float* proto    = (const float*)d_in[3];   // [4][64]
    const float* enc_w    = (const float*)d_in[4];   // [128][8192]
    const float* enc_b    = (const float*)d_in[5];   // [128]
    float* out = (float*)d_out;

    char* ws = (char*)d_ws;
    unsigned short* adj_bf = (unsigned short*)ws;                         // 8192*8192 bf16 = 128MB
    unsigned short* xk     = (unsigned short*)(ws + (size_t)134217728);   // 2048*8192 bf16 = 32MB
    float* part = (float*)(xk + (size_t)2048 * 8192);                     // 8*8192*128 f32 = 32MB
    float* hpart = part + (size_t)8 * 8192 * 128;                         // 8*2048*128 f32 = 8MB
    unsigned short* W1T = (unsigned short*)(hpart + (size_t)8 * 2048 * 128); // 128*8192 bf16 = 2MB
    unsigned short* W3T = W1T + (size_t)128 * 8192;                       // 2MB
    unsigned short* encw = W3T + (size_t)128 * 8192;                      // 128*8192 bf16 = 2MB
    float* protos_n = (float*)(encw + (size_t)128 * 8192);                // 256
    float* items_n  = protos_n + 256;                                     // 8192*64
    float* cates    = items_n + (size_t)8192 * 64;                        // 8192*4
    float* catesT   = cates + (size_t)8192 * 4;                           // 4*8192

    k_norm_protos<<<1, 256, 0, stream>>>(proto, protos_n);
    k_prep_items<<<32, 256, 0, stream>>>(item_emb, protos_n, items_n, cates, catesT);
    k_cast_bf16_x8<<<32768, 256, 0, stream>>>(adj, adj_bf);               // adj -> bf16
    k_cast_bf16_x8<<<512, 256, 0, stream>>>(enc_w, encw);                 // enc_w -> bf16
    k_xk<<<2048, 256, 0, stream>>>(rating, catesT, xk);

    // W1 = adj @ enc_w^T : partials [8][8192][128]
    k_gemm_part<<<dim3(1, 64, 8), 256, 0, stream>>>(adj_bf, encw, part, 8192, 1024, 8192, 8192, 128);
    k_reduce_T<8, false><<<128, 256, 0, stream>>>(part, nullptr, W1T);    // W1T[o][n]

    // W2 = adj @ W1 : partials, then W3T = 0.5*(W2^T + enc_w)
    k_gemm_part<<<dim3(1, 64, 8), 256, 0, stream>>>(adj_bf, W1T, part, 8192, 1024, 8192, 8192, 128);
    k_reduce_T<8, true><<<128, 256, 0, stream>>>(part, enc_w, W3T);       // W3T[o][n]

    // h = xk @ W3 : partials [8][2048][128]
    k_gemm_part<<<dim3(1, 16, 8), 256, 0, stream>>>(xk, W3T, hpart, 2048, 1024, 8192, 8192, 128);
    k_reduce_h<<<2048, 128, 0, stream>>>(hpart, enc_b, out);

    k_logits<<<dim3(32, 128), 256, 0, stream>>>(items_n, cates, out + (size_t)512 * 8192, out);
}